// Round 1
// baseline (672.969 us; speedup 1.0000x reference)
//
#include <hip/hip_runtime.h>

// 2-layer GCN on MI355X. Factorized normalization: h_hat = dinv[n]*(x@W);
// acc[v] = h_hat[v] (self-loop) + sum_{e: dst=v} h_hat[src_e]; out = dinv[v]*acc[v] + b.

namespace {
constexpr int BLK = 256;

__global__ __launch_bounds__(BLK) void k_deg_init(float* __restrict__ deg, int n) {
    int i = blockIdx.x * BLK + threadIdx.x;
    if (i < n) deg[i] = 1.0f;   // self-loop
}

__global__ __launch_bounds__(BLK) void k_deg_accum(const int* __restrict__ dst,
                                                   float* __restrict__ deg, int e) {
    int i = blockIdx.x * BLK + threadIdx.x;
    if (i < e) atomicAdd(&deg[dst[i]], 1.0f);
}

__global__ __launch_bounds__(BLK) void k_dinv(float* __restrict__ deg, int n) {
    int i = blockIdx.x * BLK + threadIdx.x;
    if (i < n) deg[i] = 1.0f / sqrtf(deg[i]);   // deg >= 1 always (self-loop)
}

// h_hat[n][c] = dinv[n] * sum_k x[n][k]*W1[k][c]; acc = h_hat (self-loop init)
__global__ __launch_bounds__(BLK) void k_gemm1(const float* __restrict__ x,
                                               const float* __restrict__ W1,
                                               const float* __restrict__ dinv,
                                               float* __restrict__ hhat,
                                               float* __restrict__ acc, int n) {
    __shared__ float W[64 * 64];
    int t = threadIdx.x;
    #pragma unroll
    for (int i = 0; i < 16; ++i) W[t + BLK * i] = W1[t + BLK * i];
    __syncthreads();
    int node = blockIdx.x * BLK + t;
    if (node >= n) return;
    float4 a[16];
    #pragma unroll
    for (int i = 0; i < 16; ++i) a[i] = make_float4(0.f, 0.f, 0.f, 0.f);
    const float* xr = x + (size_t)node * 64;
    for (int k = 0; k < 64; ++k) {
        float xv = xr[k];
        const float4* wr = (const float4*)(W + k * 64);
        #pragma unroll
        for (int c = 0; c < 16; ++c) {
            float4 w = wr[c];
            a[c].x = fmaf(xv, w.x, a[c].x);
            a[c].y = fmaf(xv, w.y, a[c].y);
            a[c].z = fmaf(xv, w.z, a[c].z);
            a[c].w = fmaf(xv, w.w, a[c].w);
        }
    }
    float d = dinv[node];
    float4* ho = (float4*)(hhat + (size_t)node * 64);
    float4* ao = (float4*)(acc + (size_t)node * 64);
    #pragma unroll
    for (int c = 0; c < 16; ++c) {
        float4 v = a[c];
        v.x *= d; v.y *= d; v.z *= d; v.w *= d;
        ho[c] = v;
        ao[c] = v;
    }
}

// one wave per edge; lane = channel (64 ch)
__global__ __launch_bounds__(BLK) void k_agg1(const int* __restrict__ src,
                                              const int* __restrict__ dst,
                                              const float* __restrict__ hhat,
                                              float* __restrict__ acc, int e) {
    int tid = blockIdx.x * BLK + threadIdx.x;
    int edge = tid >> 6;
    int c = tid & 63;
    if (edge >= e) return;
    int s = src[edge];
    int d = dst[edge];
    atomicAdd(&acc[(size_t)d * 64 + c], hhat[(size_t)s * 64 + c]);
}

// in-place: h1 = relu(dinv*acc + b1), float4 over N*16 vecs
__global__ __launch_bounds__(BLK) void k_fin1(float* __restrict__ acc,
                                              const float* __restrict__ dinv,
                                              const float* __restrict__ b1, int n) {
    int idx = blockIdx.x * BLK + threadIdx.x;
    if (idx >= n * 16) return;
    int node = idx >> 4;
    int c4 = idx & 15;
    float d = dinv[node];
    float4 v = ((float4*)acc)[idx];
    float4 b = ((const float4*)b1)[c4];
    v.x = fmaxf(fmaf(d, v.x, b.x), 0.f);
    v.y = fmaxf(fmaf(d, v.y, b.y), 0.f);
    v.z = fmaxf(fmaf(d, v.z, b.z), 0.f);
    v.w = fmaxf(fmaf(d, v.w, b.w), 0.f);
    ((float4*)acc)[idx] = v;
}

// h2_hat[n][j] = dinv[n] * sum_c h1[n][c]*W2[c][j]; acc2 = h2_hat (self-loop)
__global__ __launch_bounds__(BLK) void k_gemm2(const float* __restrict__ h1,
                                               const float* __restrict__ W2,
                                               const float* __restrict__ dinv,
                                               float* __restrict__ h2hat,
                                               float* __restrict__ acc2, int n) {
    __shared__ float W[64 * 16];
    int t = threadIdx.x;
    #pragma unroll
    for (int i = 0; i < 4; ++i) W[t + BLK * i] = W2[t + BLK * i];
    __syncthreads();
    int tid = blockIdx.x * BLK + t;
    int node = tid >> 4;
    int j = tid & 15;
    if (node >= n) return;
    const float* hr = h1 + (size_t)node * 64;
    float a = 0.f;
    #pragma unroll
    for (int c = 0; c < 64; ++c) a = fmaf(hr[c], W[c * 16 + j], a);
    a *= dinv[node];
    h2hat[tid] = a;
    acc2[tid] = a;
}

// 16 lanes per edge
__global__ __launch_bounds__(BLK) void k_agg2(const int* __restrict__ src,
                                              const int* __restrict__ dst,
                                              const float* __restrict__ h2hat,
                                              float* __restrict__ acc2, int e) {
    int tid = blockIdx.x * BLK + threadIdx.x;
    int edge = tid >> 4;
    int j = tid & 15;
    if (edge >= e) return;
    int s = src[edge];
    int d = dst[edge];
    atomicAdd(&acc2[(size_t)d * 16 + j], h2hat[(size_t)s * 16 + j]);
}

// out = dinv*acc2 + b2, float4 over N*4 vecs
__global__ __launch_bounds__(BLK) void k_fin2(const float* __restrict__ acc2,
                                              const float* __restrict__ dinv,
                                              const float* __restrict__ b2,
                                              float* __restrict__ out, int n) {
    int idx = blockIdx.x * BLK + threadIdx.x;
    if (idx >= n * 4) return;
    int node = idx >> 2;
    int j4 = idx & 3;
    float d = dinv[node];
    float4 v = ((const float4*)acc2)[idx];
    float4 b = ((const float4*)b2)[j4];
    v.x = fmaf(d, v.x, b.x);
    v.y = fmaf(d, v.y, b.y);
    v.z = fmaf(d, v.z, b.z);
    v.w = fmaf(d, v.w, b.w);
    ((float4*)out)[idx] = v;
}

} // namespace

extern "C" void kernel_launch(void* const* d_in, const int* in_sizes, int n_in,
                              void* d_out, int out_size, void* d_ws, size_t ws_size,
                              hipStream_t stream) {
    const float* x  = (const float*)d_in[0];
    const int*   ei = (const int*)d_in[1];
    const float* W1 = (const float*)d_in[2];
    const float* b1 = (const float*)d_in[3];
    const float* W2 = (const float*)d_in[4];
    const float* b2 = (const float*)d_in[5];
    float* out = (float*)d_out;

    const int N = in_sizes[0] / 64;
    const int E = in_sizes[1] / 2;
    const int* src = ei;
    const int* dst = ei + E;

    // workspace layout (256B aligned): dinv | bufA (N*64) | bufB (N*64)
    // bufA: h_hat, then reused for h2_hat (N*16) + acc2 (N*16)
    // bufB: acc1, becomes h1 in-place
    char* ws = (char*)d_ws;
    size_t off = 0;
    auto alloc = [&](size_t bytes) -> float* {
        float* p = (float*)(ws + off);
        off = (off + bytes + 255) & ~(size_t)255;
        return p;
    };
    float* dinv = alloc((size_t)N * 4);
    float* bufA = alloc((size_t)N * 64 * 4);
    float* bufB = alloc((size_t)N * 64 * 4);
    float* hhat  = bufA;
    float* acc1  = bufB;               // in-place -> h1
    float* h2hat = bufA;               // reuse (hhat dead after agg1)
    float* acc2  = bufA + (size_t)N * 16;

    const int nb_n = (N + BLK - 1) / BLK;
    const int nb_e = (E + BLK - 1) / BLK;

    k_deg_init<<<nb_n, BLK, 0, stream>>>(dinv, N);
    k_deg_accum<<<nb_e, BLK, 0, stream>>>(dst, dinv, E);
    k_dinv<<<nb_n, BLK, 0, stream>>>(dinv, N);

    k_gemm1<<<nb_n, BLK, 0, stream>>>(x, W1, dinv, hhat, acc1, N);

    long long t1 = (long long)E * 64;
    k_agg1<<<(int)((t1 + BLK - 1) / BLK), BLK, 0, stream>>>(src, dst, hhat, acc1, E);

    int t2 = N * 16;  // float4 count
    k_fin1<<<(t2 + BLK - 1) / BLK, BLK, 0, stream>>>(acc1, dinv, b1, N);

    int t3 = N * 16;  // threads: 16 per node
    k_gemm2<<<(t3 + BLK - 1) / BLK, BLK, 0, stream>>>(acc1, W2, dinv, h2hat, acc2, N);

    long long t4 = (long long)E * 16;
    k_agg2<<<(int)((t4 + BLK - 1) / BLK), BLK, 0, stream>>>(src, dst, h2hat, acc2, E);

    int t5 = N * 4;  // float4 count
    k_fin2<<<(t5 + BLK - 1) / BLK, BLK, 0, stream>>>(acc2, dinv, b2, out, N);
}

// Round 2
// 471.116 us; speedup vs baseline: 1.4285x; 1.4285x over previous
//
#include <hip/hip_runtime.h>

// 2-layer GCN, CSR-based (atomic-free) aggregation.
// h_hat = dinv[n]*(x@W1); h1[v] = relu(dinv[v]*(h_hat[v] + sum_{e:dst=v} h_hat[src_e]) + b1)
// h2_hat = dinv[n]*(h1@W2); out[v] = dinv[v]*(h2_hat[v] + sum h2_hat[src_e]) + b2

namespace {
constexpr int BLK = 256;

// ---- CSR build -------------------------------------------------------------

__global__ __launch_bounds__(BLK) void k_hist(const int* __restrict__ dst,
                                              int* __restrict__ cnt, int e) {
    int i = blockIdx.x * BLK + threadIdx.x;
    if (i < e) atomicAdd(&cnt[dst[i]], 1);
}

// per-block totals of cnt
__global__ __launch_bounds__(BLK) void k_scan_bsum(const int* __restrict__ cnt,
                                                   int* __restrict__ bsum, int n) {
    __shared__ int s[BLK];
    int i = blockIdx.x * BLK + threadIdx.x;
    int t = threadIdx.x;
    s[t] = (i < n) ? cnt[i] : 0;
    __syncthreads();
    for (int off = BLK / 2; off > 0; off >>= 1) {
        if (t < off) s[t] += s[t + off];
        __syncthreads();
    }
    if (t == 0) bsum[blockIdx.x] = s[0];
}

// single-block exclusive scan of bsum (nb <= 1024)
__global__ __launch_bounds__(1024) void k_scan_top(int* __restrict__ bsum, int nb) {
    __shared__ int s[1024];
    int t = threadIdx.x;
    int v = (t < nb) ? bsum[t] : 0;
    s[t] = v;
    __syncthreads();
    for (int off = 1; off < 1024; off <<= 1) {
        int x = (t >= off) ? s[t - off] : 0;
        __syncthreads();
        s[t] += x;
        __syncthreads();
    }
    if (t < nb) bsum[t] = s[t] - v;  // exclusive
}

// per-block exclusive scan + block offset -> rowptr, cursor; also dinv
__global__ __launch_bounds__(BLK) void k_scan_final(const int* __restrict__ cnt,
                                                    const int* __restrict__ bsum,
                                                    int* __restrict__ rowptr,
                                                    int* __restrict__ cursor,
                                                    float* __restrict__ dinv,
                                                    int n, int e_total) {
    __shared__ int s[BLK];
    int i = blockIdx.x * BLK + threadIdx.x;
    int t = threadIdx.x;
    int v = (i < n) ? cnt[i] : 0;
    s[t] = v;
    __syncthreads();
    for (int off = 1; off < BLK; off <<= 1) {
        int x = (t >= off) ? s[t - off] : 0;
        __syncthreads();
        s[t] += x;
        __syncthreads();
    }
    if (i < n) {
        int ex = s[t] - v + bsum[blockIdx.x];
        rowptr[i] = ex;
        cursor[i] = ex;
        dinv[i] = rsqrtf((float)(v + 1));   // +1 self-loop
    }
    if (i == 0) rowptr[n] = e_total;
}

__global__ __launch_bounds__(BLK) void k_scatter(const int* __restrict__ src,
                                                 const int* __restrict__ dst,
                                                 int* __restrict__ cursor,
                                                 int* __restrict__ ssrc, int e) {
    int i = blockIdx.x * BLK + threadIdx.x;
    if (i < e) {
        int p = atomicAdd(&cursor[dst[i]], 1);
        ssrc[p] = src[i];
    }
}

// ---- layer kernels ---------------------------------------------------------

// h_hat[n][c] = dinv[n] * sum_k x[n][k]*W1[k][c]
__global__ __launch_bounds__(BLK) void k_gemm1(const float* __restrict__ x,
                                               const float* __restrict__ W1,
                                               const float* __restrict__ dinv,
                                               float* __restrict__ hhat, int n) {
    __shared__ float W[64 * 64];
    int t = threadIdx.x;
    #pragma unroll
    for (int i = 0; i < 16; ++i) W[t + BLK * i] = W1[t + BLK * i];
    __syncthreads();
    int node = blockIdx.x * BLK + t;
    if (node >= n) return;
    float4 a[16];
    #pragma unroll
    for (int i = 0; i < 16; ++i) a[i] = make_float4(0.f, 0.f, 0.f, 0.f);
    const float* xr = x + (size_t)node * 64;
    for (int k = 0; k < 64; ++k) {
        float xv = xr[k];
        const float4* wr = (const float4*)(W + k * 64);
        #pragma unroll
        for (int c = 0; c < 16; ++c) {
            float4 w = wr[c];
            a[c].x = fmaf(xv, w.x, a[c].x);
            a[c].y = fmaf(xv, w.y, a[c].y);
            a[c].z = fmaf(xv, w.z, a[c].z);
            a[c].w = fmaf(xv, w.w, a[c].w);
        }
    }
    float d = dinv[node];
    float4* ho = (float4*)(hhat + (size_t)node * 64);
    #pragma unroll
    for (int c = 0; c < 16; ++c) {
        float4 v = a[c];
        v.x *= d; v.y *= d; v.z *= d; v.w *= d;
        ho[c] = v;
    }
}

// one wave per node, lane = channel (64); register accumulation, no atomics
__global__ __launch_bounds__(BLK) void k_agg1_csr(const float* __restrict__ hhat,
                                                  const int* __restrict__ rowptr,
                                                  const int* __restrict__ ssrc,
                                                  const float* __restrict__ dinv,
                                                  const float* __restrict__ b1,
                                                  float* __restrict__ h1, int n) {
    int wid = (blockIdx.x * BLK + threadIdx.x) >> 6;
    int lane = threadIdx.x & 63;
    if (wid >= n) return;
    int beg = rowptr[wid];
    int end = rowptr[wid + 1];
    float a = hhat[(size_t)wid * 64 + lane];  // self-loop
    int e = beg;
    for (; e + 2 <= end; e += 2) {
        int s0 = ssrc[e];
        int s1 = ssrc[e + 1];
        float v0 = hhat[(size_t)s0 * 64 + lane];
        float v1 = hhat[(size_t)s1 * 64 + lane];
        a += v0;
        a += v1;
    }
    if (e < end) a += hhat[(size_t)ssrc[e] * 64 + lane];
    float dv = dinv[wid];
    h1[(size_t)wid * 64 + lane] = fmaxf(fmaf(dv, a, b1[lane]), 0.f);
}

// h2_hat[n][j] = dinv[n] * sum_c h1[n][c]*W2[c][j]
__global__ __launch_bounds__(BLK) void k_gemm2(const float* __restrict__ h1,
                                               const float* __restrict__ W2,
                                               const float* __restrict__ dinv,
                                               float* __restrict__ h2hat, int n) {
    __shared__ float W[64 * 16];
    int t = threadIdx.x;
    #pragma unroll
    for (int i = 0; i < 4; ++i) W[t + BLK * i] = W2[t + BLK * i];
    __syncthreads();
    int tid = blockIdx.x * BLK + t;
    int node = tid >> 4;
    int j = tid & 15;
    if (node >= n) return;
    const float* hr = h1 + (size_t)node * 64;
    float a = 0.f;
    #pragma unroll
    for (int c = 0; c < 64; ++c) a = fmaf(hr[c], W[c * 16 + j], a);
    h2hat[tid] = a * dinv[node];
}

// one wave per node; 64 lanes = 4 edge-slots x 16 channels; shfl-reduce slots
__global__ __launch_bounds__(BLK) void k_agg2_csr(const float* __restrict__ h2hat,
                                                  const int* __restrict__ rowptr,
                                                  const int* __restrict__ ssrc,
                                                  const float* __restrict__ dinv,
                                                  const float* __restrict__ b2,
                                                  float* __restrict__ out, int n) {
    int wid = (blockIdx.x * BLK + threadIdx.x) >> 6;
    int lane = threadIdx.x & 63;
    if (wid >= n) return;
    int q = lane >> 4;      // edge slot 0..3
    int c = lane & 15;      // channel
    int beg = rowptr[wid];
    int end = rowptr[wid + 1];
    float a = 0.f;
    for (int e = beg + q; e < end; e += 4) {
        int s = ssrc[e];
        a += h2hat[(size_t)s * 16 + c];
    }
    a += __shfl_xor(a, 16, 64);
    a += __shfl_xor(a, 32, 64);
    if (q == 0) {
        float self = h2hat[(size_t)wid * 16 + c];
        out[(size_t)wid * 16 + c] = fmaf(dinv[wid], a + self, b2[c]);
    }
}

} // namespace

extern "C" void kernel_launch(void* const* d_in, const int* in_sizes, int n_in,
                              void* d_out, int out_size, void* d_ws, size_t ws_size,
                              hipStream_t stream) {
    const float* x  = (const float*)d_in[0];
    const int*   ei = (const int*)d_in[1];
    const float* W1 = (const float*)d_in[2];
    const float* b1 = (const float*)d_in[3];
    const float* W2 = (const float*)d_in[4];
    const float* b2 = (const float*)d_in[5];
    float* out = (float*)d_out;

    const int N = in_sizes[0] / 64;
    const int E = in_sizes[1] / 2;
    const int* src = ei;
    const int* dst = ei + E;

    char* ws = (char*)d_ws;
    size_t off = 0;
    auto alloc = [&](size_t bytes) -> char* {
        char* p = ws + off;
        off = (off + bytes + 255) & ~(size_t)255;
        return p;
    };
    int*   cnt    = (int*)alloc((size_t)N * 4);
    int*   rowptr = (int*)alloc(((size_t)N + 1) * 4);
    int*   cursor = (int*)alloc((size_t)N * 4);
    int*   bsum   = (int*)alloc(1024 * 4);
    float* dinv   = (float*)alloc((size_t)N * 4);
    int*   ssrc   = (int*)alloc((size_t)E * 4);
    float* hhat   = (float*)alloc((size_t)N * 64 * 4);  // reused as h2hat
    float* h1     = (float*)alloc((size_t)N * 64 * 4);
    float* h2hat  = hhat;  // hhat dead after k_agg1_csr

    const int nb_n = (N + BLK - 1) / BLK;
    const int nb_e = (E + BLK - 1) / BLK;
    const int nb_w = (int)(((long long)N * 64 + BLK - 1) / BLK);  // wave-per-node grids

    hipMemsetAsync(cnt, 0, (size_t)N * 4, stream);
    k_hist<<<nb_e, BLK, 0, stream>>>(dst, cnt, E);
    k_scan_bsum<<<nb_n, BLK, 0, stream>>>(cnt, bsum, N);
    k_scan_top<<<1, 1024, 0, stream>>>(bsum, nb_n);
    k_scan_final<<<nb_n, BLK, 0, stream>>>(cnt, bsum, rowptr, cursor, dinv, N, E);
    k_scatter<<<nb_e, BLK, 0, stream>>>(src, dst, cursor, ssrc, E);

    k_gemm1<<<nb_n, BLK, 0, stream>>>(x, W1, dinv, hhat, N);
    k_agg1_csr<<<nb_w, BLK, 0, stream>>>(hhat, rowptr, ssrc, dinv, b1, h1, N);

    int t3 = N * 16;
    k_gemm2<<<(t3 + BLK - 1) / BLK, BLK, 0, stream>>>(h1, W2, dinv, h2hat, N);
    k_agg2_csr<<<nb_w, BLK, 0, stream>>>(h2hat, rowptr, ssrc, dinv, b2, out, N);
}